// Round 10
// baseline (245.499 us; speedup 1.0000x reference)
//
#include <hip/hip_runtime.h>
#include <hip/hip_bf16.h>
#include <math.h>
#include <type_traits>

namespace {
constexpr int Bb = 256, Jj = 21, Cc = 256, Hh = 8, Dd = 256;
constexpr int Mrows = Bb * Jj;      // 5376
constexpr int HD    = Hh * Dd;      // 2048
constexpr int QKVN  = 3 * HD;       // 6144
constexpr int KNN   = 8;
constexpr int KFUSE = HD + Cc + Cc; // 2560

// ---- workspace byte offsets ----
// attb aliases the T region: T dead after precise_kernel, attn runs later.
constexpr size_t OFF_QKV   = 0;                                   // bf16 5376x6144
constexpr size_t OFF_T     = OFF_QKV   + (size_t)Mrows*QKVN*2;    // f32  5376x2048
constexpr size_t OFF_ATT   = OFF_T;                               // bf16 5376x2048 (alias)
constexpr size_t OFF_GT    = OFF_T     + (size_t)Mrows*HD*4;      // f16  2048x768
constexpr size_t OFF_JFB   = OFF_GT    + (size_t)HD*768*2;        // bf16 5376x256
constexpr size_t OFF_JFH   = OFF_JFB   + (size_t)Mrows*Cc*2;      // f16  5376x256
constexpr size_t OFF_JFL   = OFF_JFH   + (size_t)Mrows*Cc*2;      // f16  5376x256
constexpr size_t OFF_JFD   = OFF_JFL   + (size_t)Mrows*Cc*2;      // f16  5376x256
constexpr size_t OFF_H1B   = OFF_JFD   + (size_t)Mrows*Cc*2;      // bf16 5376x256
constexpr size_t OFF_H2F   = OFF_H1B   + (size_t)Mrows*Cc*2;      // f32  5376x256
constexpr size_t OFF_WQKVT = OFF_H2F   + (size_t)Mrows*Cc*4;      // bf16 2x6144x256
constexpr size_t OFF_FBT   = OFF_WQKVT + (size_t)2*QKVN*Cc*2;     // bf16 2x256x2560
constexpr size_t OFF_WVP   = OFF_FBT   + (size_t)2*Cc*KFUSE*2;    // f32  256x24
constexpr size_t OFF_VPROJ = OFF_WVP   + (size_t)Cc*24*4;         // f32  5376x24
constexpr size_t OFF_WSUM  = OFF_VPROJ + (size_t)Mrows*24*4;      // f32  256x4
constexpr size_t OFF_CRD   = OFF_WSUM  + (size_t)Cc*4*4;          // f32  5376x4
constexpr size_t OFF_NBR0  = OFF_CRD   + (size_t)Mrows*4*4;       // int  5376x8
constexpr size_t OFF_NBR1  = OFF_NBR0  + (size_t)Mrows*KNN*4;
constexpr size_t OFF_STAT  = OFF_NBR1  + (size_t)Mrows*KNN*4;     // 2 f32
} // namespace

typedef short short8 __attribute__((ext_vector_type(8)));
typedef _Float16 half8 __attribute__((ext_vector_type(8)));
typedef _Float16 half4v __attribute__((ext_vector_type(4)));
typedef unsigned short u16x8 __attribute__((ext_vector_type(8)));
typedef float f32x4 __attribute__((ext_vector_type(4)));

__device__ __forceinline__ unsigned short f2bf(float x) {
    unsigned int u = __float_as_uint(x);
    u = u + 0x7fffu + ((u >> 16) & 1u);            // round-to-nearest-even
    return (unsigned short)(u >> 16);
}
__device__ __forceinline__ float bf2f(unsigned short b) {
    return __uint_as_float(((unsigned int)b) << 16);
}

// ---------------------------------------------------------------------------
// kNN body: exact stable-argsort ranks 1..8 by (d2, index).
__device__ __forceinline__ void knn_body(int b, const float* __restrict__ src,
                                         int ld, int* __restrict__ nbr,
                                         float (*cs)[3]) {
    int t = threadIdx.x;
    if (t < Jj) {
        const float* p = src + (size_t)(b * Jj + t) * ld;
        cs[t][0] = p[0]; cs[t][1] = p[1]; cs[t][2] = p[2];
    }
    __syncthreads();
    if (t < Jj) {
        float x = cs[t][0], y = cs[t][1], z = cs[t][2];
        float d2[Jj];
        #pragma unroll
        for (int jj = 0; jj < Jj; ++jj) {
            float dx = x - cs[jj][0], dy = y - cs[jj][1], dz = z - cs[jj][2];
            d2[jj] = dx*dx + dy*dy + dz*dz;
        }
        unsigned int used = 0u;
        int out_base = (b * Jj + t) * KNN;
        #pragma unroll
        for (int r = 0; r <= KNN; ++r) {
            int best = -1; float bd = INFINITY;
            #pragma unroll
            for (int jj = 0; jj < Jj; ++jj)
                if (!((used >> jj) & 1u) && d2[jj] < bd) { bd = d2[jj]; best = jj; }
            used |= (1u << best);
            if (r > 0) nbr[out_base + r - 1] = best;
        }
    }
}

// ---------------------------------------------------------------------------
// MEGA-PREP: one launch for all input-only work.
__global__ __launch_bounds__(256)
void mega_prep_kernel(const float* __restrict__ jf,
                      const float* __restrict__ wq, const float* __restrict__ wk,
                      const float* __restrict__ wv, const float* __restrict__ wp,
                      const float* __restrict__ wsw, const float* __restrict__ wsk,
                      unsigned short* __restrict__ wqkvT,
                      unsigned short* __restrict__ fbt, float* __restrict__ stats,
                      float* __restrict__ wsum,
                      unsigned short* __restrict__ jfb, _Float16* __restrict__ jfh,
                      _Float16* __restrict__ jfl, _Float16* __restrict__ jfd,
                      _Float16* __restrict__ GT, float* __restrict__ Wvp2,
                      int* __restrict__ nbr0) {
    __shared__ __align__(16) char sm[17408];
    int bid = blockIdx.x;
    int tidx = threadIdx.x;

    if (bid < 4352) {                      // ---- weight transposes ----
        const float* src; unsigned short* dst;
        int ldin, ldout, tilesX, tile;
        constexpr size_t CH = (size_t)Cc * HD;
        if (bid < 3072) {
            int op = bid >> 9; tile = bid & 511; tilesX = 64;
            ldin = HD; ldout = Cc;
            const float* s3[3] = {wq, wk, wv};
            src = s3[op % 3] + (size_t)(op / 3) * CH;
            dst = wqkvT + (size_t)(op % 3) * HD * Cc + (size_t)(op / 3) * QKVN * Cc;
        } else if (bid < 4096) {
            int op = (bid - 3072) >> 9; tile = (bid - 3072) & 511; tilesX = 8;
            ldin = Cc; ldout = KFUSE;
            src = wp + (size_t)op * HD * Cc;
            dst = fbt + (size_t)op * Cc * KFUSE;
        } else {
            int q = bid - 4096; int op = q >> 6; tile = q & 63; tilesX = 8;
            ldin = Cc; ldout = KFUSE;
            const float* s4[4] = {wsw, wsw + (size_t)Cc * Cc, wsk, wsk};
            src = s4[op];
            dst = fbt + (size_t)(op & 1) * Cc * KFUSE + HD + (size_t)(op >> 1) * Cc;
        }
        int bx = tile % tilesX, by = tile / tilesX;
        int n0 = bx * 32, k0 = by * 32;
        float (*t)[33] = (float(*)[33])sm;
        int r = tidx >> 3, c4 = (tidx & 7) * 4;
        float4 v = *(const float4*)&src[(size_t)(k0 + r) * ldin + n0 + c4];
        t[r][c4+0] = v.x; t[r][c4+1] = v.y; t[r][c4+2] = v.z; t[r][c4+3] = v.w;
        __syncthreads();
        ushort4 o;
        o.x = f2bf(t[c4+0][r]); o.y = f2bf(t[c4+1][r]);
        o.z = f2bf(t[c4+2][r]); o.w = f2bf(t[c4+3][r]);
        *(ushort4*)&dst[(size_t)(n0 + r) * ldout + k0 + c4] = o;
    } else if (bid == 4352) {              // ---- wsum + stats zero ----
        int e = tidx;
        float4 o;
        o.x = wsw[(size_t)e*Dd + 0] + wsk[(size_t)e*Dd + 0];
        o.y = wsw[(size_t)e*Dd + 1] + wsk[(size_t)e*Dd + 1];
        o.z = wsw[(size_t)e*Dd + 2] + wsk[(size_t)e*Dd + 2];
        o.w = 0.0f;
        *(float4*)&wsum[e*4] = o;
        if (e < 2) stats[e] = 0.0f;
    } else if (bid < 5697) {               // ---- cvt_split ----
        int i = (bid - 4353) * 256 + tidx;
        float4 v = ((const float4*)jf)[i];
        float x[4] = {v.x, v.y, v.z, v.w};
        ushort4 ob; half4v oh, ol, od;
        #pragma unroll
        for (int u = 0; u < 4; ++u) {
            ((unsigned short*)&ob)[u] = f2bf(x[u]);
            _Float16 h = (_Float16)x[u];
            oh[u] = h;
            ol[u] = (_Float16)((x[u] - (float)h) * 16.0f);
            od[u] = (_Float16)(x[u] * 0.0078125f);   // /128
        }
        ((ushort4*)jfb)[i] = ob;
        ((half4v*)jfh)[i] = oh;
        ((half4v*)jfl)[i] = ol;
        ((half4v*)jfd)[i] = od;
    } else if (bid < 5825) {               // ---- g_gemm -> GT (fp16-split) ----
        int q = bid - 5697;
        int h = q >> 4, rem = q & 15;
        int m0 = (rem >> 2) * 64, n0 = (rem & 3) * 64;
        float (*As)[68] = (float(*)[68])sm;
        float (*Ws)[68] = (float(*)[68])(sm + 8704);
        int ty = tidx >> 4, tx = tidx & 15;
        float acc[4][4] = {};
        for (int kb = 0; kb < 256; kb += 32) {
            #pragma unroll
            for (int it = 0; it < 2; ++it) {
                int c = tidx + it * 256;
                int row = c >> 3, col = (c & 7) * 4;
                float4 v = *(const float4*)&wq[(size_t)(m0 + row)*HD + h*256 + kb + col];
                float4 u = *(const float4*)&wk[(size_t)(n0 + row)*HD + h*256 + kb + col];
                As[col+0][row] = v.x; As[col+1][row] = v.y;
                As[col+2][row] = v.z; As[col+3][row] = v.w;
                Ws[col+0][row] = u.x; Ws[col+1][row] = u.y;
                Ws[col+2][row] = u.z; Ws[col+3][row] = u.w;
            }
            __syncthreads();
            #pragma unroll
            for (int kk = 0; kk < 32; ++kk) {
                float4 a = *(const float4*)&As[kk][ty*4];
                float4 b = *(const float4*)&Ws[kk][tx*4];
                float av[4] = {a.x, a.y, a.z, a.w};
                float bv[4] = {b.x, b.y, b.z, b.w};
                #pragma unroll
                for (int i = 0; i < 4; ++i)
                    #pragma unroll
                    for (int j = 0; j < 4; ++j)
                        acc[i][j] += av[i] * bv[j];
            }
            __syncthreads();
        }
        #pragma unroll
        for (int j = 0; j < 4; ++j) {
            int n = h*256 + n0 + tx*4 + j;
            half4v hi, hs, lo;
            #pragma unroll
            for (int i = 0; i < 4; ++i) {
                float g = acc[i][j];
                _Float16 gh = (_Float16)g;
                hi[i] = gh;
                hs[i] = (_Float16)(g * 0.0625f);
                lo[i] = (_Float16)((g - (float)gh) * 128.0f);
            }
            _Float16* base = &GT[(size_t)n*768 + m0 + ty*4];
            *(half4v*)(base)       = hi;
            *(half4v*)(base + 256) = hs;
            *(half4v*)(base + 512) = lo;
        }
    } else if (bid < 5833) {               // ---- wvp ----
        int h = bid - 5825;
        float (*wpc)[3] = (float(*)[3])sm;
        int t = tidx;
        const float* p = &wp[(size_t)(h*256 + t) * Cc];
        wpc[t][0] = p[0]; wpc[t][1] = p[1]; wpc[t][2] = p[2];
        __syncthreads();
        const float* vr = &wv[(size_t)t*HD + h*256];
        float a0=0, a1=0, a2=0;
        for (int d = 0; d < 256; ++d) {
            float v = vr[d];
            a0 += v*wpc[d][0]; a1 += v*wpc[d][1]; a2 += v*wpc[d][2];
        }
        float* o = &Wvp2[(size_t)t*24 + h*3];
        o[0]=a0; o[1]=a1; o[2]=a2;
    } else {                               // ---- knn layer 0 ----
        knn_body(bid - 5833, jf, Cc, nbr0, (float(*)[3])sm);
    }
}

// ---------------------------------------------------------------------------
// 16-bit MFMA GEMM core, XOR-swizzled LDS.
template<int BM, int BN, int BK, int NSEG, bool RELU_STATS, bool OUT_BF16, bool F16>
__device__ __forceinline__
void gemm_core(unsigned short* As, unsigned short* Bs, float* red,
               int bm, int bn,
               const unsigned short* __restrict__ A0, int lda0, int klen0,
               const unsigned short* __restrict__ A1, int lda1, int klen1,
               const unsigned short* __restrict__ A2, int lda2, int klen2,
               const unsigned short* __restrict__ Bt, int ldb,
               void* __restrict__ Cv, int ldc, float* __restrict__ stat) {
    constexpr int WM = BM/2, WN = BN/2;
    constexpr int MW = WM/16, NW = WN/16, KW = BK/32;
    constexpr int CHUNKA = BM*BK/8;
    constexpr int CHUNKB = BN*BK/8;
    constexpr int KB8 = BK/8;
    constexpr int SWZ = KB8 - 1;
    using frag = std::conditional_t<F16, half8, short8>;

    int tid = threadIdx.x;
    int wid = tid >> 6, lane = tid & 63;
    int wr = wid >> 1, wc = wid & 1;

    f32x4 acc[MW][NW];
    #pragma unroll
    for (int m = 0; m < MW; ++m)
        #pragma unroll
        for (int n = 0; n < NW; ++n)
            acc[m][n] = (f32x4){0.f, 0.f, 0.f, 0.f};

    const unsigned short* Aseg[3] = {A0, A1, A2};
    const int ldas[3] = {lda0, lda1, lda2};
    const int klens[3] = {klen0, klen1, klen2};

    int kglob = 0;
    for (int seg = 0; seg < NSEG; ++seg) {
        const unsigned short* A = Aseg[seg];
        const int lda = ldas[seg];
        const int klen = klens[seg];
        for (int k0 = 0; k0 < klen; k0 += BK) {
            #pragma unroll
            for (int it = 0; it < CHUNKA/256; ++it) {
                int c = tid + it*256;
                int row = c / KB8;
                int kp = (c % KB8) ^ (row & SWZ);
                __builtin_amdgcn_global_load_lds(
                    (const __attribute__((address_space(1))) unsigned int*)
                        (A + (size_t)(bm + row)*lda + k0 + kp*8),
                    (__attribute__((address_space(3))) unsigned int*)(As + c*8),
                    16, 0, 0);
            }
            #pragma unroll
            for (int it = 0; it < CHUNKB/256; ++it) {
                int c = tid + it*256;
                int row = c / KB8;
                int kp = (c % KB8) ^ (row & SWZ);
                __builtin_amdgcn_global_load_lds(
                    (const __attribute__((address_space(1))) unsigned int*)
                        (Bt + (size_t)(bn + row)*ldb + kglob + k0 + kp*8),
                    (__attribute__((address_space(3))) unsigned int*)(Bs + c*8),
                    16, 0, 0);
            }
            __syncthreads();
            #pragma unroll
            for (int kp = 0; kp < KW; ++kp) {
                frag af[MW], bf[NW];
                int cbase = kp*4 + (lane >> 4);
                #pragma unroll
                for (int m = 0; m < MW; ++m) {
                    int r = wr*WM + m*16 + (lane & 15);
                    af[m] = *(const frag*)&As[r*BK + ((cbase ^ (r & SWZ))*8)];
                }
                #pragma unroll
                for (int n = 0; n < NW; ++n) {
                    int r = wc*WN + n*16 + (lane & 15);
                    bf[n] = *(const frag*)&Bs[r*BK + ((cbase ^ (r & SWZ))*8)];
                }
                #pragma unroll
                for (int m = 0; m < MW; ++m)
                    #pragma unroll
                    for (int n = 0; n < NW; ++n) {
                        if constexpr (F16)
                            acc[m][n] = __builtin_amdgcn_mfma_f32_16x16x32_f16(
                                af[m], bf[n], acc[m][n], 0, 0, 0);
                        else
                            acc[m][n] = __builtin_amdgcn_mfma_f32_16x16x32_bf16(
                                af[m], bf[n], acc[m][n], 0, 0, 0);
                    }
            }
            __syncthreads();
        }
        kglob += klen;
    }

    int cr = (lane >> 4)*4, cc = lane & 15;
    float bsum = 0.0f;
    #pragma unroll
    for (int m = 0; m < MW; ++m)
        #pragma unroll
        for (int n = 0; n < NW; ++n)
            #pragma unroll
            for (int j = 0; j < 4; ++j) {
                float v = acc[m][n][j];
                if (RELU_STATS) { v = fmaxf(v, 0.0f); bsum += v; }
                size_t row = bm + wr*WM + m*16 + cr + j;
                size_t col = bn + wc*WN + n*16 + cc;
                if (OUT_BF16) ((unsigned short*)Cv)[row*ldc + col] = f2bf(v);
                else          ((float*)Cv)[row*ldc + col] = v;
            }
    if (RELU_STATS) {
        #pragma unroll
        for (int sft = 1; sft < 64; sft <<= 1) bsum += __shfl_xor(bsum, sft);
        if (lane == 0) red[wid] = bsum;
        __syncthreads();
        if (tid == 0) atomicAdd(stat, red[0] + red[1] + red[2] + red[3]);
    }
}

// ---------------------------------------------------------------------------
// COMBO: y<48 -> layer-0 QKV gemm; y in [48,64) -> fp16-split T-gemm;
// y in [64,80) -> vproj.
__global__ __launch_bounds__(256)
void combo_kernel(const unsigned short* __restrict__ jfb,
                  const unsigned short* __restrict__ wqkvT,
                  unsigned short* __restrict__ QKVb,
                  const _Float16* __restrict__ jfh, const _Float16* __restrict__ jfl,
                  const _Float16* __restrict__ jfd, const _Float16* __restrict__ GT,
                  float* __restrict__ Tm,
                  const float* __restrict__ jf, const float* __restrict__ Wvp2,
                  float* __restrict__ vproj) {
    __shared__ __align__(16) char smem[32784];
    unsigned short* As = (unsigned short*)smem;
    unsigned short* Bs = (unsigned short*)(smem + 16384);
    float* red = (float*)(smem + 32768);
    int x = blockIdx.x, y = blockIdx.y;
    if (y < 48) {
        gemm_core<128,128,64,1,false,true,false>(As, Bs, red, x*128, y*128,
            jfb, Cc, Cc, jfb, Cc, 0, jfb, Cc, 0, wqkvT, Cc, QKVb, QKVN, nullptr);
    } else if (y < 64) {
        gemm_core<128,128,64,3,false,false,true>(As, Bs, red, x*128, (y-48)*128,
            (const unsigned short*)jfh, Cc, Cc, (const unsigned short*)jfl, Cc, Cc,
            (const unsigned short*)jfd, Cc, Cc, (const unsigned short*)GT, 768,
            Tm, HD, nullptr);
    } else {
        int q = (y - 64) * 42 + x;
        float (*hr)[256] = (float(*)[256])smem;
        float* wl = (float*)(smem + 8192);
        int t = threadIdx.x;
        int j0 = q * 8;
        #pragma unroll
        for (int i = 0; i < 6; ++i)
            *(float4*)&wl[t*4 + i*1024] = *(const float4*)&Wvp2[t*4 + i*1024];
        {
            int r = t >> 5, c = (t & 31) * 8;
            const float* src = &jf[(size_t)(j0 + r)*Cc + c];
            *(float4*)&hr[r][c]   = *(const float4*)src;
            *(float4*)&hr[r][c+4] = *(const float4*)(src + 4);
        }
        __syncthreads();
        int r = t >> 5, o = t & 31;
        if (o < 24) {
            float a = 0.0f;
            for (int e = 0; e < 256; ++e) a += hr[r][e] * wl[e*24 + o];
            vproj[(size_t)(j0 + r)*24 + o] = a;
        }
    }
}

// ---------------------------------------------------------------------------
// standalone MFMA gemm (for layer-1 QKV)
template<int BM, int BN, int BK, int NSEG, bool RELU_STATS, bool OUT_BF16, bool F16 = false>
__global__ __launch_bounds__(256)
void gemm_bt_kernel(const unsigned short* __restrict__ A0, int lda0, int klen0,
                    const unsigned short* __restrict__ A1, int lda1, int klen1,
                    const unsigned short* __restrict__ A2, int lda2, int klen2,
                    const unsigned short* __restrict__ Bt, int ldb,
                    void* __restrict__ Cv, int ldc, float* __restrict__ stat) {
    __shared__ __align__(16) unsigned short As[BM*BK];
    __shared__ __align__(16) unsigned short Bs[BN*BK];
    __shared__ float red[4];
    gemm_core<BM,BN,BK,NSEG,RELU_STATS,OUT_BF16,F16>(
        As, Bs, red, blockIdx.x*BM, blockIdx.y*BN,
        A0, lda0, klen0, A1, lda1, klen1, A2, lda2, klen2,
        Bt, ldb, Cv, ldc, stat);
}

// ---------------------------------------------------------------------------
// fused epilogue gemm (+ optional layer-1 kNN in extra y-blocks)
template<bool OUT_BF16, bool DO_KNN>
__global__ __launch_bounds__(256)
void fused_kernel(const unsigned short* __restrict__ att,
                  const unsigned short* __restrict__ hseg,
                  const unsigned short* __restrict__ h0seg,
                  const unsigned short* __restrict__ fbtL,
                  void* __restrict__ Cv, float* __restrict__ stat,
                  const float* __restrict__ crd, int* __restrict__ nbr1) {
    __shared__ __align__(16) char smem[16400];
    if (DO_KNN && blockIdx.y >= 4) {
        int b = (blockIdx.y - 4) * 84 + blockIdx.x;
        if (b < Bb) knn_body(b, crd, 4, nbr1, (float(*)[3])smem);
        return;
    }
    unsigned short* As = (unsigned short*)smem;
    unsigned short* Bs = (unsigned short*)(smem + 8192);
    float* red = (float*)(smem + 16384);
    gemm_core<64,64,64,3,true,OUT_BF16,false>(
        As, Bs, red, blockIdx.x*64, blockIdx.y*64,
        att, HD, HD, hseg, Cc, Cc, h0seg, Cc, Cc,
        fbtL, KFUSE, Cv, Cc, stat);
}

// ---------------------------------------------------------------------------
// precise layer-0 coords
__global__ __launch_bounds__(64)
void precise_kernel(const float* __restrict__ T, const float* __restrict__ h0,
                    const int* __restrict__ nbr, const float* __restrict__ vproj,
                    const float* __restrict__ wsum, float* __restrict__ crd) {
    int i = blockIdx.x;
    int b = i / Jj;
    int l = threadIdx.x;
    __shared__ float Ts[8][260];
    __shared__ float nb[8][260];
    __shared__ float hi[256];
    #pragma unroll
    for (int u = 0; u < 8; ++u) {
        int idx = u*64 + l;
        float4 v = *(const float4*)&T[(size_t)i*HD + idx*4];
        int hh = idx >> 6, dd = (idx & 63) * 4;
        *(float4*)&Ts[hh][dd] = v;
    }
    *(float4*)&hi[l*4] = *(const float4*)&h0[(size_t)i*Cc + l*4];
    int kq = l >> 3, s = l & 7;
    int njs = nbr[i*KNN + kq];
    const float* nrow = &h0[(size_t)(b*Jj + njs)*Cc];
    #pragma unroll
    for (int u = 0; u < 8; ++u)
        *(float4*)&nb[kq][(s*8+u)*4] = *(const float4*)&nrow[(s*8+u)*4];
    __syncthreads();

    int k = l >> 3, h = l & 7;
    float sacc = 0;
    #pragma unroll 8
    for (int d = 0; d < 256; d += 4) {
        float4 tv = *(const float4*)&Ts[h][d];
        float4 nv = *(const float4*)&nb[k][d];
        sacc += tv.x*nv.x + tv.y*nv.y + tv.z*nv.z + tv.w*nv.w;
    }
    float sc = sacc * 0.0625f;
    sc = (sc >= 0.0f) ? sc : 0.2f * sc;
    float m = sc;
    m = fmaxf(m, __shfl_xor(m, 8));
    m = fmaxf(m, __shfl_xor(m, 16));
    m = fmaxf(m, __shfl_xor(m, 32));
    float e = expf(sc - m);
    float den = e;
    den += __shfl_xor(den, 8); den += __shfl_xor(den, 16); den += __shfl_xor(den, 32);
    float w = e / den;

    int njk = nbr[i*KNN + k];
    const float* vp = &vproj[(size_t)(b*Jj + njk)*24 + h*3];
    float t0 = w * vp[0], t1 = w * vp[1], t2 = w * vp[2];
    #pragma unroll
    for (int u = 0; u < 4; ++u) {
        int e4 = l*4 + u;
        float hv = hi[e4];
        float4 wv = *(const float4*)&wsum[e4*4];
        t0 += hv * wv.x; t1 += hv * wv.y; t2 += hv * wv.z;
    }
    #pragma unroll
    for (int sft = 1; sft < 64; sft <<= 1) {
        t0 += __shfl_xor(t0, sft); t1 += __shfl_xor(t1, sft); t2 += __shfl_xor(t2, sft);
    }
    if (l == 0) {
        crd[i*4+0] = fmaxf(t0, 0.0f);
        crd[i*4+1] = fmaxf(t1, 0.0f);
        crd[i*4+2] = fmaxf(t2, 0.0f);
        crd[i*4+3] = 0.0f;
    }
}

// ---------------------------------------------------------------------------
// attention v3: one block per (batch, head-pair). Q/K/V slices (21x512 bf16)
// staged in LDS once -> every QKV element fetched exactly once from cache.
// Scores: 168 threads x (i,k) pair, both heads. Softmax: 42 threads.
// V-pass: all 256 threads, LDS-resident V, coalesced stores.
__global__ __launch_bounds__(256)
void attn_kernel(const unsigned short* __restrict__ QKV,
                 const int* __restrict__ nbr, unsigned short* __restrict__ att) {
    constexpr int PAD = 520;               // 512 + 8 ushorts -> rows shift banks
    __shared__ unsigned short Qs[Jj][PAD];
    __shared__ unsigned short Ks[Jj][PAD];
    __shared__ unsigned short Vs[Jj][PAD];
    __shared__ float Sw[Jj][2][KNN];
    __shared__ int nbs[Jj*KNN];
    int b = blockIdx.x, hp = blockIdx.y;
    int tid = threadIdx.x;

    const unsigned short* base = QKV + (size_t)b*Jj*QKVN + hp*512;
    for (int c = tid; c < Jj*64; c += 256) {
        int r = c >> 6, g = c & 63;
        const unsigned short* src = base + (size_t)r*QKVN + g*8;
        *(u16x8*)&Qs[r][g*8] = *(const u16x8*)(src);
        *(u16x8*)&Ks[r][g*8] = *(const u16x8*)(src + HD);
        *(u16x8*)&Vs[r][g*8] = *(const u16x8*)(src + 2*HD);
    }
    if (tid < Jj*KNN) nbs[tid] = nbr[b*Jj*KNN + tid];
    __syncthreads();

    // ---- scores (both heads) ----
    if (tid < Jj*KNN) {
        int i = tid >> 3, n = nbs[tid];
        float d0 = 0.0f, d1 = 0.0f;
        #pragma unroll 8
        for (int g = 0; g < 32; ++g) {
            u16x8 q = *(const u16x8*)&Qs[i][g*8];
            u16x8 kk = *(const u16x8*)&Ks[n][g*8];
            #pragma unroll
            for (int u = 0; u < 8; ++u) d0 += bf2f(q[u]) * bf2f(kk[u]);
        }
        #pragma unroll 8
        for (int g = 32; g < 64; ++g) {
            u16x8 q = *(const u16x8*)&Qs[i][g*8];
            u16x8 kk = *(const u16x8*)&Ks[n][g*8];
            #pragma unroll
            for (int u = 0; u < 8; ++u) d1 += bf2f(q[u]) * bf2f(kk[u]);
        }
        int k = tid & 7;
        float s0 = d0 * 0.0625f; s0 = (s0 >= 0.0f) ? s0 : 0.2f * s0;
        float s1 = d1 * 0.0625f; s1 = (s1 >= 0.0f) ? s1 : 0.2f * s1;
        Sw[i][0][k] = s0;
        Sw[i][1][k] = s1;
    }
    __syncthreads();

    // ---- softmax over k (42 threads) ----
    if (tid < Jj*2) {
        int i = tid >> 1, h = tid & 1;
        float mx = -INFINITY;
        #pragma unroll
        for (int k = 0; k < KNN; ++k) mx = fmaxf(mx, Sw[i][h][k]);
        float e[KNN]; float den = 0.0f;
        #pragma unroll
        for (int k = 0; k < KNN; ++k) { e[k] = expf(Sw[i][h][k] - mx); den += e[k]; }
        float inv = 1.0f / den;
        #pragma unroll
        for (int k = 0; k < KNN; ++k) Sw[i][h][k] = e[k] * inv;
    }
    __syncthreads();

    // ---- V pass ----
    for (int c = tid; c < Jj*64; c += 256) {
        int i = c >> 6, g = c & 63;
        int h = g >> 5;
        float acc[8] = {};
        #pragma unroll
        for (int k = 0; k < KNN; ++k) {
            float w = Sw[i][h][k];
            u16x8 v = *(const u16x8*)&Vs[nbs[i*KNN + k]][g*8];
            #pragma unroll
            for (int u = 0; u < 8; ++u) acc[u] += w * bf2f(v[u]);
        }
        u16x8 o;
        #pragma unroll
        for (int u = 0; u < 8; ++u) o[u] = f2bf(acc[u]);
        *(u16x8*)&att[(size_t)(b*Jj + i)*HD + hp*512 + g*8] = o;
    }
}

// ---------------------------------------------------------------------------
__global__ __launch_bounds__(64)
void final_kernel(const float* __restrict__ h, const float* __restrict__ fcw,
                  const float* __restrict__ fcb, const float* __restrict__ stats,
                  float* __restrict__ out) {
    int row = blockIdx.x, lane = threadIdx.x;
    const float4 hv = *(const float4*)(h + (size_t)row*Cc + lane*4);
    float a0=0, a1=0, a2=0;
    const float hx[4] = {hv.x, hv.y, hv.z, hv.w};
    #pragma unroll
    for (int i = 0; i < 4; ++i) {
        int c = lane*4 + i;
        a0 += hx[i]*fcw[c*3+0]; a1 += hx[i]*fcw[c*3+1]; a2 += hx[i]*fcw[c*3+2];
    }
    #pragma unroll
    for (int s = 32; s > 0; s >>= 1) {
        a0 += __shfl_xor(a0, s); a1 += __shfl_xor(a1, s); a2 += __shfl_xor(a2, s);
    }
    if (lane == 0) {
        out[row*3+0] = a0 + fcb[0];
        out[row*3+1] = a1 + fcb[1];
        out[row*3+2] = a2 + fcb[2];
        if (row == 0)
            out[(size_t)Mrows*3] =
                (stats[0] + stats[1]) * (0.5f / ((float)Mrows * (float)Cc));
    }
}

// ---------------------------------------------------------------------------
extern "C" void kernel_launch(void* const* d_in, const int* in_sizes, int n_in,
                              void* d_out, int out_size, void* d_ws, size_t ws_size,
                              hipStream_t stream) {
    (void)in_sizes; (void)n_in; (void)out_size; (void)ws_size;
    const float* jf     = (const float*)d_in[0];
    const float* wq     = (const float*)d_in[1];
    const float* wk     = (const float*)d_in[2];
    const float* wv     = (const float*)d_in[3];
    const float* wp     = (const float*)d_in[4];
    const float* wsw    = (const float*)d_in[5];
    const float* wskip0 = (const float*)d_in[6];
    const float* fcw    = (const float*)d_in[7];
    const float* fcb    = (const float*)d_in[8];
    float* out = (float*)d_out;

    char* wsb = (char*)d_ws;
    unsigned short* QKVb  = (unsigned short*)(wsb + OFF_QKV);
    float*          Tm    = (float*)(wsb + OFF_T);
    unsigned short* attb  = (unsigned short*)(wsb + OFF_ATT);   // aliases T
    _Float16*       GT    = (_Float16*)(wsb + OFF_GT);
    unsigned short* jfb   = (unsigned short*)(wsb + OFF_JFB);
    _Float16*       jfh   = (_Float16*)(wsb + OFF_JFH);
    _Float16*       jfl   = (_Float16*)(wsb + OFF_JFL);
    _Float16*       jfd   = (_Float16*)(wsb + OFF_JFD);
    unsigned short* h1b   = (unsigned short*)(wsb + OFF_H1B);
    float*          h2f   = (float*)(wsb + OFF_H2F);
    unsigned short* wqkvT = (unsigned short*)(wsb + OFF_WQKVT);
    unsigned short* fbt   = (unsigned short*)(wsb + OFF_FBT);
    float*          Wvp   = (float*)(wsb + OFF_WVP);
    float*          vproj = (float*)(wsb + OFF_VPROJ);
    float*          wsum  = (float*)(wsb + OFF_WSUM);
    float*          crd   = (float*)(wsb + OFF_CRD);
    int*            nbr0  = (int*)(wsb + OFF_NBR0);
    int*            nbr1  = (int*)(wsb + OFF_NBR1);
    float*          stats = (float*)(wsb + OFF_STAT);

    // 1. all input-only prep in one launch
    mega_prep_kernel<<<6089, 256, 0, stream>>>(jf, wq, wk, wv, wp, wsw, wskip0,
                                               wqkvT, fbt, stats, wsum,
                                               jfb, jfh, jfl, jfd, GT, Wvp, nbr0);
    // 2. layer-0 QKV gemm + fp16-split T-gemm + vproj in one launch
    combo_kernel<<<dim3(42, 80), 256, 0, stream>>>(jfb, wqkvT, QKVb,
                                                   jfh, jfl, jfd, GT, Tm,
                                                   jf, Wvp, vproj);
    // 3. precise layer-0 coords (consumes Tm; attb overwrites it after)
    precise_kernel<<<Mrows, 64, 0, stream>>>(Tm, jf, nbr0, vproj, wsum, crd);
    // 4. layer-0 attention
    attn_kernel<<<dim3(Bb, 4), 256, 0, stream>>>(QKVb, nbr0, attb);
    // 5. layer-0 fused output gemm + layer-1 kNN
    fused_kernel<true, true><<<dim3(84, 8), 256, 0, stream>>>(
        attb, jfb, jfb, fbt, h1b, &stats[0], crd, nbr1);
    // 6. layer-1 QKV gemm
    gemm_bt_kernel<128,128,64,1,false,true><<<dim3(Mrows/128, QKVN/128), 256, 0, stream>>>(
        h1b, Cc, Cc, h1b, Cc, 0, h1b, Cc, 0, wqkvT + (size_t)QKVN*Cc, Cc, QKVb, QKVN, nullptr);
    // 7. layer-1 attention
    attn_kernel<<<dim3(Bb, 4), 256, 0, stream>>>(QKVb, nbr1, attb);
    // 8. layer-1 fused output gemm
    fused_kernel<false, false><<<dim3(84, 4), 256, 0, stream>>>(
        attb, h1b, jfb, fbt + (size_t)Cc*KFUSE, h2f, &stats[1], nullptr, nullptr);
    // 9. final
    final_kernel<<<Mrows, 64, 0, stream>>>(h2f, fcw, fcb, stats, out);
}